// Round 1
// baseline (37244.263 us; speedup 1.0000x reference)
//
#include <hip/hip_runtime.h>
#include <cmath>

// TimeLSTMCell: B=64, S=512, E=256, H=512, fp32.
// Persistent kernel: 256 WGs x 512 threads, one grid barrier per time step.
// WG (bg,cg): bg in [0,4) owns 16 batches, cg in [0,64) owns 8 hidden columns.
// Thread t: pair = t&127 (bl = pair>>3 in [0,16), jl = pair&7), kq = t>>7 (K quarter).
// Per (b,j): 4 gate dots (K = 512 h-part + 256 x-part, fused) + 1 c_s1 dot (K=512),
// split across 4 kq threads, reduced through LDS; kq==0 thread does the pointwise LSTM.
// h state lives in d_out itself (step s reads outputs[:,s-1,:]); c double-buffers in ws.

#define Bdim 64
#define Sdim 512
#define Edim 256
#define Hdim 512
#define NWG 256
#define NTHREADS 512
#define NB 16
#define NJ 8

// Reset-free grid barrier: per-WG monotonically increasing flag, released with
// agent-scope release store (emits L2 writeback on gfx950), spun with relaxed
// agent-scope loads, followed by one agent fence (cache invalidate) per WG.
// Works for any initial flag state < 1: 0xAAAAAAAA poison is negative as int,
// fresh zeros are 0. Targets run 1..513, monotone within a launch.
__device__ __forceinline__ void grid_barrier(int* flags, int target) {
    __syncthreads();  // all prior global stores of this WG issued & drained (vmcnt 0 before s_barrier)
    if (threadIdx.x == 0) {
        __threadfence();  // belt-and-suspenders release (wbL2 at agent scope)
        __hip_atomic_store(&flags[blockIdx.x], target, __ATOMIC_RELEASE,
                           __HIP_MEMORY_SCOPE_AGENT);
    }
    if (threadIdx.x < NWG) {
        while (__hip_atomic_load(&flags[threadIdx.x], __ATOMIC_RELAXED,
                                 __HIP_MEMORY_SCOPE_AGENT) < target) {
            __builtin_amdgcn_s_sleep(2);
        }
    }
    __syncthreads();
    if (threadIdx.x == 0) {
        __threadfence();  // acquire side: invalidate stale L1/L2 lines (shared per CU/XCD)
    }
    __syncthreads();
}

__global__ __launch_bounds__(NTHREADS, 2) void tlstm_persistent(
    const float* __restrict__ x,       // [B,S,E]
    const float* __restrict__ ts,      // [B,S]
    const float* __restrict__ Wall,    // [4H,H] row-major, gate order f,i,o,c
    const float* __restrict__ Wall_b,  // [4H]
    const float* __restrict__ Uall,    // [4H,E]
    const float* __restrict__ Uall_b,  // [4H]
    const float* __restrict__ Wd,      // [H,H]
    const float* __restrict__ Wd_b,    // [H]
    float* __restrict__ out,           // outputs [B,S,H] | h_f [B,H] | c_f [B,H]
    float* __restrict__ ws)            // flags[256] (int) | pad | h0[B*H] | cb0[B*H] | cb1[B*H]
{
    __shared__ float red[4][128][5];

    int*   flags = (int*)ws;
    float* h0    = ws + 512;            // 2 KB offset, 16B aligned
    float* cb0   = h0 + Bdim * Hdim;
    float* cb1   = cb0 + Bdim * Hdim;

    const int t    = threadIdx.x;
    const int pair = t & 127;
    const int kq   = t >> 7;
    const int jl   = pair & 7;
    const int bl   = pair >> 3;
    const int bg   = blockIdx.x >> 6;
    const int cg   = blockIdx.x & 63;
    const int b    = bg * NB + bl;
    const int j    = cg * NJ + jl;

    // Zero-init h0 and cb0 (d_ws is poisoned 0xAA before every launch).
    const int gidx = blockIdx.x * NTHREADS + t;  // 0..131071
    if (gidx < 2 * Bdim * Hdim) h0[gidx] = 0.0f;

    grid_barrier(flags, 1);

    // Weight row pointers are invariant across steps (stay hot in L1/L2).
    // Gate g column j -> row g*H + j of Wall/Uall; c_s1 column j -> row j of Wd.
    const float4* wrow0 = (const float4*)(Wall + (size_t)(0 * Hdim + j) * Hdim + kq * 128);
    const float4* wrow1 = (const float4*)(Wall + (size_t)(1 * Hdim + j) * Hdim + kq * 128);
    const float4* wrow2 = (const float4*)(Wall + (size_t)(2 * Hdim + j) * Hdim + kq * 128);
    const float4* wrow3 = (const float4*)(Wall + (size_t)(3 * Hdim + j) * Hdim + kq * 128);
    const float4* urow0 = (const float4*)(Uall + (size_t)(0 * Hdim + j) * Edim + kq * 64);
    const float4* urow1 = (const float4*)(Uall + (size_t)(1 * Hdim + j) * Edim + kq * 64);
    const float4* urow2 = (const float4*)(Uall + (size_t)(2 * Hdim + j) * Edim + kq * 64);
    const float4* urow3 = (const float4*)(Uall + (size_t)(3 * Hdim + j) * Edim + kq * 64);
    const float4* drow  = (const float4*)(Wd + (size_t)j * Hdim + kq * 128);

    float* cb[2] = {cb0, cb1};

    for (int s = 0; s < Sdim; ++s) {
        const float* hbase = (s == 0)
            ? (h0 + b * Hdim)
            : (out + (size_t)b * Sdim * Hdim + (size_t)(s - 1) * Hdim);
        const float* cbase = cb[s & 1] + b * Hdim;
        float*       cnext = cb[(s + 1) & 1];

        const float4* h4 = (const float4*)(hbase + kq * 128);
        const float4* c4 = (const float4*)(cbase + kq * 128);
        const float4* x4 = (const float4*)(x + (size_t)b * Sdim * Edim
                                             + (size_t)s * Edim + kq * 64);

        float af = 0.f, ai = 0.f, ao = 0.f, ag = 0.f, ad = 0.f;

        // h-part of the 4 gate dots: one h load feeds 4 weight streams.
        #pragma unroll 4
        for (int k = 0; k < 32; ++k) {
            float4 hv = h4[k];
            float4 w0 = wrow0[k], w1 = wrow1[k], w2 = wrow2[k], w3 = wrow3[k];
            af += hv.x * w0.x + hv.y * w0.y + hv.z * w0.z + hv.w * w0.w;
            ai += hv.x * w1.x + hv.y * w1.y + hv.z * w1.z + hv.w * w1.w;
            ao += hv.x * w2.x + hv.y * w2.y + hv.z * w2.z + hv.w * w2.w;
            ag += hv.x * w3.x + hv.y * w3.y + hv.z * w3.z + hv.w * w3.w;
        }
        // c_s1 dot.
        #pragma unroll 4
        for (int k = 0; k < 32; ++k) {
            float4 cv = c4[k];
            float4 wd = drow[k];
            ad += cv.x * wd.x + cv.y * wd.y + cv.z * wd.z + cv.w * wd.w;
        }
        // x-part of the 4 gate dots (fused u-projection: no [B,S,4H] scratch).
        #pragma unroll 4
        for (int k = 0; k < 16; ++k) {
            float4 xv = x4[k];
            float4 u0 = urow0[k], u1 = urow1[k], u2 = urow2[k], u3 = urow3[k];
            af += xv.x * u0.x + xv.y * u0.y + xv.z * u0.z + xv.w * u0.w;
            ai += xv.x * u1.x + xv.y * u1.y + xv.z * u1.z + xv.w * u1.w;
            ao += xv.x * u2.x + xv.y * u2.y + xv.z * u2.z + xv.w * u2.w;
            ag += xv.x * u3.x + xv.y * u3.y + xv.z * u3.z + xv.w * u3.w;
        }

        red[kq][pair][0] = af;
        red[kq][pair][1] = ai;
        red[kq][pair][2] = ao;
        red[kq][pair][3] = ag;
        red[kq][pair][4] = ad;
        __syncthreads();

        if (kq == 0) {
            float vf = red[0][pair][0] + red[1][pair][0] + red[2][pair][0] + red[3][pair][0];
            float vi = red[0][pair][1] + red[1][pair][1] + red[2][pair][1] + red[3][pair][1];
            float vo = red[0][pair][2] + red[1][pair][2] + red[2][pair][2] + red[3][pair][2];
            float vg = red[0][pair][3] + red[1][pair][3] + red[2][pair][3] + red[3][pair][3];
            float vd = red[0][pair][4] + red[1][pair][4] + red[2][pair][4] + red[3][pair][4];

            vf += Wall_b[0 * Hdim + j] + Uall_b[0 * Hdim + j];
            vi += Wall_b[1 * Hdim + j] + Uall_b[1 * Hdim + j];
            vo += Wall_b[2 * Hdim + j] + Uall_b[2 * Hdim + j];
            vg += Wall_b[3 * Hdim + j] + Uall_b[3 * Hdim + j];

            float cs1  = tanhf(vd + Wd_b[j]);
            float dec  = 1.0f / logf(2.7182818284590452f + ts[b * Sdim + s]);
            float cp   = cbase[j];
            float cadj = (cp - cs1) + cs1 * dec;

            float f  = 1.0f / (1.0f + expf(-vf));
            float i  = 1.0f / (1.0f + expf(-vi));
            float o  = 1.0f / (1.0f + expf(-vo));
            float g  = tanhf(vg);
            float cn = f * cadj + i * g;
            float hn = o * tanhf(cn);

            cnext[b * Hdim + j] = cn;
            out[(size_t)b * Sdim * Hdim + (size_t)s * Hdim + j] = hn;
        }

        grid_barrier(flags, s + 2);  // h_new/c_new visible before step s+1 reads
    }

    // Epilogue: h_f = outputs[:, S-1, :], c_f = final c (S even -> cb0).
    if (gidx < Bdim * Hdim) {
        const int bb = gidx >> 9;       // / Hdim
        const int jj = gidx & (Hdim - 1);
        float* hf = out + (size_t)Bdim * Sdim * Hdim;
        float* cf = hf + Bdim * Hdim;
        hf[gidx] = out[(size_t)bb * Sdim * Hdim + (size_t)(Sdim - 1) * Hdim + jj];
        cf[gidx] = cb0[gidx];
    }
}

extern "C" void kernel_launch(void* const* d_in, const int* in_sizes, int n_in,
                              void* d_out, int out_size, void* d_ws, size_t ws_size,
                              hipStream_t stream) {
    const float* x      = (const float*)d_in[0];  // inputs [B,S,E]
    const float* ts     = (const float*)d_in[1];  // timestamps [B,S]
    const float* Wall   = (const float*)d_in[2];  // W_all_w [4H,H]
    const float* Wall_b = (const float*)d_in[3];  // W_all_b [4H]
    const float* Uall   = (const float*)d_in[4];  // U_all_w [4H,E]
    const float* Uall_b = (const float*)d_in[5];  // U_all_b [4H]
    const float* Wd     = (const float*)d_in[6];  // W_d_w [H,H]
    const float* Wd_b   = (const float*)d_in[7];  // W_d_b [H]

    tlstm_persistent<<<NWG, NTHREADS, 0, stream>>>(
        x, ts, Wall, Wall_b, Uall, Uall_b, Wd, Wd_b,
        (float*)d_out, (float*)d_ws);
}

// Round 2
// 8474.543 us; speedup vs baseline: 4.3948x; 4.3948x over previous
//
#include <hip/hip_runtime.h>
#include <cmath>

// TimeLSTMCell B=64, S=512, E=256, H=512 fp32.
// Persistent kernel, 256 WGs x 512 thr (1 WG/CU, forced by 135 KB LDS).
// WG (bg,cg): bg in [0,4) -> 16 batches, cg in [0,64) -> 8 hidden cols.
// Per step: stage h[16x512], c[16x512] into LDS via device-scope (sc1) loads;
// phase A: gates GEMM 32 rows x 16 b x K=768, thread tile = 4 rows x 8 batches,
//          K split 32 ways; phase B: d-dots 8 rows x 16 b x K=512, tile 2x8, K/64.
// LDS-padded reductions (stride 33 / 65 -> conflict-free column sums).
// Cross-WG h/c exchange: relaxed AGENT-scope atomics (sc0 sc1: bypass the
// non-coherent per-XCD L2, coherent at LIC). NO cache-wide fences -> weights
// stay hot in L1/L2 across all 512 steps.
// Barrier: __syncthreads() drains vmcnt(0) per wave before s_barrier (m97),
// so all sc1 stores are globally visible before the relaxed sc1 flag store.

#define Bdim 64
#define Sdim 512
#define Edim 256
#define Hdim 512
#define NWG  256
#define NT   512

__device__ __forceinline__ float ld_dev(const float* p) {
    return __hip_atomic_load(p, __ATOMIC_RELAXED, __HIP_MEMORY_SCOPE_AGENT);
}
__device__ __forceinline__ void st_dev(float* p, float v) {
    __hip_atomic_store(p, v, __ATOMIC_RELAXED, __HIP_MEMORY_SCOPE_AGENT);
}
__device__ __forceinline__ float dot4(float4 a, float4 b) {
    return a.x*b.x + a.y*b.y + a.z*b.z + a.w*b.w;
}

// Fence-free grid barrier (per-access coherence makes fences unnecessary).
__device__ __forceinline__ void grid_barrier(int* flags, int target) {
    __syncthreads();  // drains vmcnt(0): all this WG's sc1 stores are at LIC
    if (threadIdx.x == 0) {
        __hip_atomic_store(&flags[blockIdx.x], target, __ATOMIC_RELAXED,
                           __HIP_MEMORY_SCOPE_AGENT);
    }
    if (threadIdx.x < NWG) {
        while (__hip_atomic_load(&flags[threadIdx.x], __ATOMIC_RELAXED,
                                 __HIP_MEMORY_SCOPE_AGENT) < target) {
            __builtin_amdgcn_s_sleep(1);
        }
    }
    __syncthreads();
}

__global__ __launch_bounds__(NT, 2) void tlstm(
    const float* __restrict__ x,       // [B,S,E]
    const float* __restrict__ ts,      // [B,S]
    const float* __restrict__ Wall,    // [4H,H]
    const float* __restrict__ Wall_b,  // [4H]
    const float* __restrict__ Uall,    // [4H,E]
    const float* __restrict__ Uall_b,  // [4H]
    const float* __restrict__ Wd,      // [H,H]
    const float* __restrict__ Wd_b,    // [H]
    float* __restrict__ out,           // [B,S,H] | h_f[B,H] | c_f[B,H]
    float* __restrict__ ws)            // flags[256] | pad | cb0[B*H] | cb1[B*H]
{
    // LDS pool: c_s[16*512] | redA[512*33] | gv[512] | h_s[16*512] (redB[128*65] aliases h_s)
    __shared__ float pool[33920];
    float* c_s  = pool;            // [16][512]
    float* redA = pool + 8192;     // [512][33]
    float* gv   = pool + 25088;    // [512]
    float* h_s  = pool + 25600;    // [16][512]
    float* redB = pool + 25600;    // [128][65], alias of h_s (safe: sequenced)

    int*   flags = (int*)ws;
    float* cb0   = ws + 512;
    float* cb1   = cb0 + Bdim * Hdim;
    float* cb[2] = {cb0, cb1};

    const int t  = threadIdx.x;
    const int bg = blockIdx.x >> 6;   // 0..3
    const int cg = blockIdx.x & 63;   // 0..63
    const int b0 = bg * 16;
    const int j0 = cg * 8;

    // Phase A roles: 8 col-groups (jlA = col within WG) x 2 batch halves x 32 K-slices
    const int jlA   = t >> 6;
    const int bgrpA = (t >> 5) & 1;
    const int kqA   = t & 31;
    // Phase B roles: 4 row-pairs x 2 batch halves x 64 K-slices
    const int rgB   = t >> 7;
    const int bgrpB = (t >> 6) & 1;
    const int kqB   = t & 63;

    // Step-invariant weight row pointers (plain cached loads; stay hot in L1/L2).
    const float4* wr0 = (const float4*)(Wall + (size_t)(0 * Hdim + j0 + jlA) * Hdim);
    const float4* wr1 = (const float4*)(Wall + (size_t)(1 * Hdim + j0 + jlA) * Hdim);
    const float4* wr2 = (const float4*)(Wall + (size_t)(2 * Hdim + j0 + jlA) * Hdim);
    const float4* wr3 = (const float4*)(Wall + (size_t)(3 * Hdim + j0 + jlA) * Hdim);
    const float4* ur0 = (const float4*)(Uall + (size_t)(0 * Hdim + j0 + jlA) * Edim);
    const float4* ur1 = (const float4*)(Uall + (size_t)(1 * Hdim + j0 + jlA) * Edim);
    const float4* ur2 = (const float4*)(Uall + (size_t)(2 * Hdim + j0 + jlA) * Edim);
    const float4* ur3 = (const float4*)(Uall + (size_t)(3 * Hdim + j0 + jlA) * Edim);
    const float4* dr0 = (const float4*)(Wd + (size_t)(j0 + rgB * 2 + 0) * Hdim);
    const float4* dr1 = (const float4*)(Wd + (size_t)(j0 + rgB * 2 + 1) * Hdim);

    const float* xbaseA = x + (size_t)(b0 + bgrpA * 8) * Sdim * Edim;

    for (int s = 0; s < Sdim; ++s) {
        // ---- stage h, c into LDS (device-scope loads: coherent at LIC) ----
        if (s == 0) {
            #pragma unroll
            for (int i = 0; i < 16; ++i) {
                h_s[i * 512 + t] = 0.0f;
                c_s[i * 512 + t] = 0.0f;
            }
        } else {
            const float* hsrc = out + (size_t)b0 * Sdim * Hdim + (size_t)(s - 1) * Hdim;
            const float* csrc = cb[s & 1] + b0 * Hdim;
            #pragma unroll
            for (int i = 0; i < 16; ++i) {
                h_s[i * 512 + t] = ld_dev(hsrc + (size_t)i * Sdim * Hdim + t);
                c_s[i * 512 + t] = ld_dev(csrc + i * Hdim + t);
            }
        }
        __syncthreads();

        // ---- phase A: gate partial dots (4 gates x 8 batches per thread) ----
        float accA[4][8];
        #pragma unroll
        for (int g = 0; g < 4; ++g)
            #pragma unroll
            for (int i = 0; i < 8; ++i) accA[g][i] = 0.0f;

        #pragma unroll
        for (int cc = 0; cc < 4; ++cc) {           // h-part: K 0..511
            const int f4i = cc * 32 + kqA;
            float4 w0 = wr0[f4i], w1 = wr1[f4i], w2 = wr2[f4i], w3 = wr3[f4i];
            #pragma unroll
            for (int i = 0; i < 8; ++i) {
                float4 hv = *(const float4*)(h_s + (bgrpA * 8 + i) * 512 + f4i * 4);
                accA[0][i] += dot4(hv, w0);
                accA[1][i] += dot4(hv, w1);
                accA[2][i] += dot4(hv, w2);
                accA[3][i] += dot4(hv, w3);
            }
        }
        #pragma unroll
        for (int cc = 0; cc < 2; ++cc) {           // x-part: K 512..767
            const int f4i = cc * 32 + kqA;
            float4 u0 = ur0[f4i], u1 = ur1[f4i], u2 = ur2[f4i], u3 = ur3[f4i];
            #pragma unroll
            for (int i = 0; i < 8; ++i) {
                float4 xv = *((const float4*)(xbaseA + (size_t)i * Sdim * Edim
                                              + (size_t)s * Edim) + f4i);
                accA[0][i] += dot4(xv, u0);
                accA[1][i] += dot4(xv, u1);
                accA[2][i] += dot4(xv, u2);
                accA[3][i] += dot4(xv, u3);
            }
        }

        // ---- phase B: c_s1 partial dots (2 rows x 8 batches per thread) ----
        float accB[2][8];
        #pragma unroll
        for (int r = 0; r < 2; ++r)
            #pragma unroll
            for (int i = 0; i < 8; ++i) accB[r][i] = 0.0f;

        #pragma unroll
        for (int cc = 0; cc < 2; ++cc) {
            const int f4i = cc * 64 + kqB;
            float4 d0 = dr0[f4i], d1 = dr1[f4i];
            #pragma unroll
            for (int i = 0; i < 8; ++i) {
                float4 cv = *(const float4*)(c_s + (bgrpB * 8 + i) * 512 + f4i * 4);
                accB[0][i] += dot4(cv, d0);
                accB[1][i] += dot4(cv, d1);
            }
        }

        // ---- write gate partials (stride-33 pad: conflict-free) ----
        #pragma unroll
        for (int g = 0; g < 4; ++g)
            #pragma unroll
            for (int i = 0; i < 8; ++i)
                redA[((jlA * 4 + g) * 16 + bgrpA * 8 + i) * 33 + kqA] = accA[g][i];
        __syncthreads();  // everyone done reading h_s -> redB may clobber it

        // ---- write d partials (aliases h_s; stride-65 pad) + reduce gates ----
        #pragma unroll
        for (int r = 0; r < 2; ++r)
            #pragma unroll
            for (int i = 0; i < 8; ++i)
                redB[((rgB * 2 + r) * 16 + bgrpB * 8 + i) * 65 + kqB] = accB[r][i];
        {
            const int o  = t;            // o = (jl*4+g)*16 + bl
            const int r  = o >> 4;
            const int g  = r & 3;
            const int j  = j0 + (r >> 2);
            float sum = 0.0f;
            #pragma unroll
            for (int k = 0; k < 32; ++k) sum += redA[o * 33 + k];
            gv[o] = sum + Wall_b[g * Hdim + j] + Uall_b[g * Hdim + j];
        }
        __syncthreads();

        // ---- reduce d + pointwise LSTM update (128 threads: one per (jl,bl)) ----
        if (t < 128) {
            const int jl = t >> 4;
            const int bl = t & 15;
            const int j  = j0 + jl;
            const int b  = b0 + bl;
            float dsum = 0.0f;
            #pragma unroll
            for (int k = 0; k < 64; ++k) dsum += redB[t * 65 + k];
            const float cs1  = tanhf(dsum + Wd_b[j]);
            const float dec  = 1.0f / logf(2.7182818284590452f + ts[b * Sdim + s]);
            const float cp   = c_s[bl * 512 + j];
            const float cadj = (cp - cs1) + cs1 * dec;

            const float vf = gv[(jl * 4 + 0) * 16 + bl];
            const float vi = gv[(jl * 4 + 1) * 16 + bl];
            const float vo = gv[(jl * 4 + 2) * 16 + bl];
            const float vg = gv[(jl * 4 + 3) * 16 + bl];
            const float f  = 1.0f / (1.0f + expf(-vf));
            const float ii = 1.0f / (1.0f + expf(-vi));
            const float oo = 1.0f / (1.0f + expf(-vo));
            const float gg = tanhf(vg);
            const float cn = f * cadj + ii * gg;
            const float hn = oo * tanhf(cn);

            st_dev(cb[(s + 1) & 1] + b * Hdim + j, cn);
            st_dev(out + (size_t)b * Sdim * Hdim + (size_t)s * Hdim + j, hn);
            if (s == Sdim - 1) {
                float* hf = out + (size_t)Bdim * Sdim * Hdim;
                float* cf = hf + Bdim * Hdim;
                hf[b * Hdim + j] = hn;
                cf[b * Hdim + j] = cn;
            }
        }

        grid_barrier(flags, s + 1);
    }
}

extern "C" void kernel_launch(void* const* d_in, const int* in_sizes, int n_in,
                              void* d_out, int out_size, void* d_ws, size_t ws_size,
                              hipStream_t stream) {
    const float* x      = (const float*)d_in[0];
    const float* ts     = (const float*)d_in[1];
    const float* Wall   = (const float*)d_in[2];
    const float* Wall_b = (const float*)d_in[3];
    const float* Uall   = (const float*)d_in[4];
    const float* Uall_b = (const float*)d_in[5];
    const float* Wd     = (const float*)d_in[6];
    const float* Wd_b   = (const float*)d_in[7];

    tlstm<<<NWG, NT, 0, stream>>>(x, ts, Wall, Wall_b, Uall, Uall_b, Wd, Wd_b,
                                  (float*)d_out, (float*)d_ws);
}